// Round 9
// baseline (24.230 us; speedup 1.0000x reference)
//
#include <hip/hip_runtime.h>
#include <math.h>

#define EPS 1e-12f

typedef float v2f __attribute__((ext_vector_type(2)));

constexpr int Bn = 64;             // batch
constexpr int Np = 512;            // N == M == 512
constexpr int ROW = 4;             // owners per lane (2 packed v2f chains)
constexpr int OSPLIT = 2;          // owner splits per (b, pass)
constexpr int OWN = Np / OSPLIT;   // 256 owners per block (64 lanes x ROW)
constexpr int TPB = 1024;          // 16 waves; each wave takes one k-sixteenth
constexpr int KSPLIT = 16;
constexpr int KCH = Np / KSPLIT;   // 32 loop points per wave
constexpr int NBLK = Bn * 2 * OSPLIT;  // 256 blocks == 1/CU, all co-resident

// Single dispatch. Each lane owns 4 adjacent owner points as two packed v2f
// chains (VOP3P packed fp32). Loop points are loaded per-lane from global
// (same address across the wave -> one coalesced L1-resident request). NOT
// readfirstlane'd: keeping the index "divergent" forces VMEM (in-order,
// partial vmcnt waits) instead of SMEM (out-of-order, lgkmcnt(0)-only, which
// defeats software pipelining). Explicit 2-deep rotation prefetch hides L1
// latency under the packed-VALU compute. 16 k-chunk partials combine in LDS,
// sqrt + fixed-order wave sum -> one value per block, published NEGATIVE
// (epoch encoding) with agent release. Block 0 spin-waits (all 256 blocks
// co-resident at 1/CU), accepts a slot only when x < -1e-5 (0xAA poison
// = -3e-13 and stale +1.0 resets both fail), resets slots to +1.0 for the
// next graph replay, then does the deterministic fixed-order 256-tree sum.
__global__ __launch_bounds__(TPB, 4) void chamfer_fused_kernel(
        const float* __restrict__ p, const float* __restrict__ q,
        float* __restrict__ partial, float* __restrict__ outp) {
    const int bid  = blockIdx.x;
    const int b    = bid & (Bn - 1);
    const int pass = (bid >> 6) & 1;
    const int oc   = bid >> 7;
    const float* A = (pass == 0) ? p : q;   // owner array (2,Bn,Np,4)
    const float* L = (pass == 0) ? q : p;   // loop array

    const int t  = threadIdx.x;
    const int ot = t & 63;
    const int kh = t >> 6;                  // wave-uniform in fact, divergent to LLVM

    const float4* are = (const float4*)(A + (size_t)b * Np * 4);
    const float4* aim = (const float4*)(A + (size_t)(Bn + b) * Np * 4);
    const int o = oc * OWN + ot * ROW;
    const float4 a0 = are[o],     a1 = are[o + 1];
    const float4 a2 = are[o + 2], a3 = are[o + 3];
    const float4 c0 = aim[o],     c1 = aim[o + 1];
    const float4 c2 = aim[o + 2], c3 = aim[o + 3];
    const v2f prx01 = {a0.x, a1.x}, pry01 = {a0.y, a1.y};
    const v2f prz01 = {a0.z, a1.z}, prw01 = {a0.w, a1.w};
    const v2f pix01 = {c0.x, c1.x}, piy01 = {c0.y, c1.y};
    const v2f piz01 = {c0.z, c1.z}, piw01 = {c0.w, c1.w};
    const v2f prx23 = {a2.x, a3.x}, pry23 = {a2.y, a3.y};
    const v2f prz23 = {a2.z, a3.z}, prw23 = {a2.w, a3.w};
    const v2f pix23 = {c2.x, c3.x}, piy23 = {c2.y, c3.y};
    const v2f piz23 = {c2.z, c3.z}, piw23 = {c2.w, c3.w};

    const float4* lre = (const float4*)(L + (size_t)b * Np * 4);
    const float4* lim = (const float4*)(L + (size_t)(Bn + b) * Np * 4);

    v2f smin01 = {3.4e38f, 3.4e38f};
    v2f smin23 = {3.4e38f, 3.4e38f};

    auto eval = [&](const float4& qr, const float4& qi) {
        {   // owners 0,1
            v2f drx = prx01 - qr.x, dry = pry01 - qr.y;
            v2f drz = prz01 - qr.z, drw = prw01 - qr.w;
            v2f dix = pix01 - qi.x, diy = piy01 - qi.y;
            v2f diz = piz01 - qi.z, diw = piw01 - qi.w;
            v2f mr  = drx*drx - dry*dry - drz*drz - drw*drw;
            v2f mi  = drx*dix - dry*diy - drz*diz - drw*diw;
            v2f mi2 = mi + mi;
            smin01 = __builtin_elementwise_min(smin01, mr*mr + mi2*mi2);
        }
        {   // owners 2,3
            v2f drx = prx23 - qr.x, dry = pry23 - qr.y;
            v2f drz = prz23 - qr.z, drw = prw23 - qr.w;
            v2f dix = pix23 - qi.x, diy = piy23 - qi.y;
            v2f diz = piz23 - qi.z, diw = piw23 - qi.w;
            v2f mr  = drx*drx - dry*dry - drz*drz - drw*drw;
            v2f mi  = drx*dix - dry*diy - drz*diz - drw*diw;
            v2f mi2 = mi + mi;
            smin23 = __builtin_elementwise_min(smin23, mr*mr + mi2*mi2);
        }
    };

    const int k0 = kh * KCH;
    // 2-deep rotation: buffers a (even iters) and b (odd iters).
    float4 qr_a = lre[k0],     qi_a = lim[k0];
    float4 qr_b = lre[k0 + 1], qi_b = lim[k0 + 1];
    #pragma unroll 2
    for (int i = 0; i < KCH; i += 2) {
        {
            const float4 ur = qr_a, ui = qi_a;
            const int kf = k0 + ((i + 2) & (KCH - 1));   // wrap: stay in-slice
            qr_a = lre[kf]; qi_a = lim[kf];
            eval(ur, ui);
        }
        {
            const float4 ur = qr_b, ui = qi_b;
            const int kf = k0 + ((i + 3) & (KCH - 1));
            qr_b = lre[kf]; qi_b = lim[kf];
            eval(ur, ui);
        }
    }

    __shared__ v2f sredA[TPB], sredB[TPB];
    __shared__ float red[NBLK];
    sredA[t] = smin01;
    sredB[t] = smin23;
    __syncthreads();

    if (t < 64) {
        v2f mA = smin01, mB = smin23;      // kh==0 lanes hold their own chunk
        #pragma unroll
        for (int w = 1; w < KSPLIT; ++w) {
            mA = __builtin_elementwise_min(mA, sredA[t + w * 64]);
            mB = __builtin_elementwise_min(mB, sredB[t + w * 64]);
        }
        float v = sqrtf(mA.x + EPS) + sqrtf(mA.y + EPS)
                + sqrtf(mB.x + EPS) + sqrtf(mB.y + EPS);
        #pragma unroll
        for (int off = 32; off > 0; off >>= 1)
            v += __shfl_down(v, off, 64);
        if (t == 0)                        // publish as negative (epoch tag)
            __hip_atomic_store(&partial[bid], -v,
                               __ATOMIC_RELEASE, __HIP_MEMORY_SCOPE_AGENT);
    }

    if (bid == 0) {                        // fixed reducer block
        if (t < NBLK) {
            float x = __hip_atomic_load(&partial[t],
                          __ATOMIC_ACQUIRE, __HIP_MEMORY_SCOPE_AGENT);
            while (x >= -1e-5f) {          // reject poison/stale; wait fresh
                __builtin_amdgcn_s_sleep(1);
                x = __hip_atomic_load(&partial[t],
                        __ATOMIC_ACQUIRE, __HIP_MEMORY_SCOPE_AGENT);
            }
            red[t] = -x;
            __hip_atomic_store(&partial[t], 1.0f,   // reset for next replay
                               __ATOMIC_RELAXED, __HIP_MEMORY_SCOPE_AGENT);
        }
        __syncthreads();
        for (int s = NBLK / 2; s > 0; s >>= 1) {
            if (t < s) red[t] += red[t + s];
            __syncthreads();
        }
        if (t == 0) outp[0] = red[0];
    }
}

extern "C" void kernel_launch(void* const* d_in, const int* in_sizes, int n_in,
                              void* d_out, int out_size, void* d_ws, size_t ws_size,
                              hipStream_t stream) {
    const float* p = (const float*)d_in[0];   // (2, 64, 512, 4) fp32
    const float* q = (const float*)d_in[1];   // (2, 64, 512, 4) fp32
    float* out     = (float*)d_out;
    float* partial = (float*)d_ws;            // 256 floats

    chamfer_fused_kernel<<<dim3(NBLK), dim3(TPB), 0, stream>>>(p, q, partial, out);
}

// Round 10
// 20.255 us; speedup vs baseline: 1.1963x; 1.1963x over previous
//
#include <hip/hip_runtime.h>
#include <math.h>

#define EPS 1e-12f

typedef float v2f __attribute__((ext_vector_type(2)));
typedef float v8f __attribute__((ext_vector_type(8)));

constexpr int Bn = 64;             // batch
constexpr int Np = 512;            // N == M == 512
constexpr int ROW = 4;             // owners per lane (2 packed v2f chains)
constexpr int OSPLIT = 2;          // owner splits per (b, pass)
constexpr int OWN = Np / OSPLIT;   // 256 owners per block (64 lanes x ROW)
constexpr int TPB = 1024;          // 16 waves; each wave takes one k-sixteenth
constexpr int KSPLIT = 16;
constexpr int KCH = Np / KSPLIT;   // 32 loop points per wave
constexpr int NGRP = KCH / 2;      // 16 s_load_dwordx8 groups (2 points each)
constexpr int NBLK = Bn * 2 * OSPLIT;  // 256 blocks == 1/CU, all co-resident

// Single dispatch (R8 structure, best so far). Each lane owns 4 adjacent
// owner points as two packed v2f chains (VOP3P packed fp32). Loop points are
// wave-uniform scalar loads, widened to v8f (s_load_dwordx8, 2 points per
// load) to halve SMEM events and give the scheduler long hoistable loads --
// targeting the residual lgkmcnt serialization. 16 k-chunk partials combine
// in LDS, sqrt + fixed-order wave sum -> one value per block, published
// NEGATIVE (epoch encoding) with agent release. Block 0 spin-waits (all 256
// blocks co-resident at 1/CU), accepts a slot only when x < -1e-5 (0xAA
// poison = -3e-13 and stale +1.0 resets both fail), resets slots to +1.0 for
// the next graph replay, then does the deterministic fixed-order 256-sum.
__global__ __launch_bounds__(TPB, 4) void chamfer_fused_kernel(
        const float* __restrict__ p, const float* __restrict__ q,
        float* __restrict__ partial, float* __restrict__ outp) {
    const int bid  = blockIdx.x;
    const int b    = bid & (Bn - 1);
    const int pass = (bid >> 6) & 1;
    const int oc   = bid >> 7;
    const float* A = (pass == 0) ? p : q;   // owner array (2,Bn,Np,4)
    const float* L = (pass == 0) ? q : p;   // loop array

    const int t  = threadIdx.x;
    const int ot = t & 63;
    const int kh = __builtin_amdgcn_readfirstlane(t >> 6);  // wave-uniform chunk

    const float4* are = (const float4*)(A + (size_t)b * Np * 4);
    const float4* aim = (const float4*)(A + (size_t)(Bn + b) * Np * 4);
    const int o = oc * OWN + ot * ROW;
    const float4 a0 = are[o],     a1 = are[o + 1];
    const float4 a2 = are[o + 2], a3 = are[o + 3];
    const float4 c0 = aim[o],     c1 = aim[o + 1];
    const float4 c2 = aim[o + 2], c3 = aim[o + 3];
    const v2f prx01 = {a0.x, a1.x}, pry01 = {a0.y, a1.y};
    const v2f prz01 = {a0.z, a1.z}, prw01 = {a0.w, a1.w};
    const v2f pix01 = {c0.x, c1.x}, piy01 = {c0.y, c1.y};
    const v2f piz01 = {c0.z, c1.z}, piw01 = {c0.w, c1.w};
    const v2f prx23 = {a2.x, a3.x}, pry23 = {a2.y, a3.y};
    const v2f prz23 = {a2.z, a3.z}, prw23 = {a2.w, a3.w};
    const v2f pix23 = {c2.x, c3.x}, piy23 = {c2.y, c3.y};
    const v2f piz23 = {c2.z, c3.z}, piw23 = {c2.w, c3.w};

    // Loop arrays viewed as 2-point (32B) groups: s_load_dwordx8.
    const v8f* lre8 = (const v8f*)(L + (size_t)b * Np * 4);
    const v8f* lim8 = (const v8f*)(L + (size_t)(Bn + b) * Np * 4);

    v2f smin01 = {3.4e38f, 3.4e38f};
    v2f smin23 = {3.4e38f, 3.4e38f};

    auto eval = [&](float qrx, float qry, float qrz, float qrw,
                    float qix, float qiy, float qiz, float qiw) {
        {   // owners 0,1
            v2f drx = prx01 - qrx, dry = pry01 - qry;
            v2f drz = prz01 - qrz, drw = prw01 - qrw;
            v2f dix = pix01 - qix, diy = piy01 - qiy;
            v2f diz = piz01 - qiz, diw = piw01 - qiw;
            v2f mr  = drx*drx - dry*dry - drz*drz - drw*drw;
            v2f mi  = drx*dix - dry*diy - drz*diz - drw*diw;
            v2f mi2 = mi + mi;
            smin01 = __builtin_elementwise_min(smin01, mr*mr + mi2*mi2);
        }
        {   // owners 2,3
            v2f drx = prx23 - qrx, dry = pry23 - qry;
            v2f drz = prz23 - qrz, drw = prw23 - qrw;
            v2f dix = pix23 - qix, diy = piy23 - qiy;
            v2f diz = piz23 - qiz, diw = piw23 - qiw;
            v2f mr  = drx*drx - dry*dry - drz*drz - drw*drw;
            v2f mi  = drx*dix - dry*diy - drz*diz - drw*diw;
            v2f mi2 = mi + mi;
            smin23 = __builtin_elementwise_min(smin23, mr*mr + mi2*mi2);
        }
    };

    const int g0 = kh * NGRP;
    #pragma unroll 4
    for (int g = 0; g < NGRP; ++g) {
        const v8f qr = lre8[g0 + g];        // wave-uniform -> s_load_dwordx8
        const v8f qi = lim8[g0 + g];
        eval(qr[0], qr[1], qr[2], qr[3], qi[0], qi[1], qi[2], qi[3]);
        eval(qr[4], qr[5], qr[6], qr[7], qi[4], qi[5], qi[6], qi[7]);
    }

    __shared__ v2f sredA[TPB], sredB[TPB];
    __shared__ float red[NBLK];
    sredA[t] = smin01;
    sredB[t] = smin23;
    __syncthreads();

    if (t < 64) {
        v2f mA = smin01, mB = smin23;      // kh==0 lanes hold their own chunk
        #pragma unroll
        for (int w = 1; w < KSPLIT; ++w) {
            mA = __builtin_elementwise_min(mA, sredA[t + w * 64]);
            mB = __builtin_elementwise_min(mB, sredB[t + w * 64]);
        }
        float v = sqrtf(mA.x + EPS) + sqrtf(mA.y + EPS)
                + sqrtf(mB.x + EPS) + sqrtf(mB.y + EPS);
        #pragma unroll
        for (int off = 32; off > 0; off >>= 1)
            v += __shfl_down(v, off, 64);
        if (t == 0)                        // publish as negative (epoch tag)
            __hip_atomic_store(&partial[bid], -v,
                               __ATOMIC_RELEASE, __HIP_MEMORY_SCOPE_AGENT);
    }

    if (bid == 0) {                        // fixed reducer block
        if (t < NBLK) {
            float x = __hip_atomic_load(&partial[t],
                          __ATOMIC_ACQUIRE, __HIP_MEMORY_SCOPE_AGENT);
            while (x >= -1e-5f) {          // reject poison/stale; wait fresh
                __builtin_amdgcn_s_sleep(1);
                x = __hip_atomic_load(&partial[t],
                        __ATOMIC_ACQUIRE, __HIP_MEMORY_SCOPE_AGENT);
            }
            red[t] = -x;
            __hip_atomic_store(&partial[t], 1.0f,   // reset for next replay
                               __ATOMIC_RELAXED, __HIP_MEMORY_SCOPE_AGENT);
        }
        __syncthreads();
        for (int s = NBLK / 2; s > 0; s >>= 1) {
            if (t < s) red[t] += red[t + s];
            __syncthreads();
        }
        if (t == 0) outp[0] = red[0];
    }
}

extern "C" void kernel_launch(void* const* d_in, const int* in_sizes, int n_in,
                              void* d_out, int out_size, void* d_ws, size_t ws_size,
                              hipStream_t stream) {
    const float* p = (const float*)d_in[0];   // (2, 64, 512, 4) fp32
    const float* q = (const float*)d_in[1];   // (2, 64, 512, 4) fp32
    float* out     = (float*)d_out;
    float* partial = (float*)d_ws;            // 256 floats

    chamfer_fused_kernel<<<dim3(NBLK), dim3(TPB), 0, stream>>>(p, q, partial, out);
}